// Round 19
// baseline (245.784 us; speedup 1.0000x reference)
//
#include <hip/hip_runtime.h>
#include <stdint.h>

#define S 4096
#define D 1024
#define H 16
#define HD 64
#define NSPLIT 2

#define QK_SCALE 0.18033688011112042f  // (1/sqrt(64)) * log2(e)

typedef short short8  __attribute__((ext_vector_type(8)));
typedef float floatx4 __attribute__((ext_vector_type(4)));
typedef float floatx16 __attribute__((ext_vector_type(16)));

__device__ __forceinline__ unsigned short f2bf(float f) {
  union { float f; unsigned int i; } x; x.f = f;
  unsigned int r = x.i + 0x7FFFu + ((x.i >> 16) & 1u);
  return (unsigned short)(r >> 16);
}

#if defined(__has_builtin)
#if __has_builtin(__builtin_amdgcn_cvt_pk_bf16_f32)
#define HAVE_PK_BF16 1
#endif
#if __has_builtin(__builtin_amdgcn_exp2f)
#define HAVE_RAW_EXP2 1
#endif
#endif

__device__ __forceinline__ unsigned int pkbf(float a, float b) {
#ifdef HAVE_PK_BF16
  typedef __bf16 bf2_t __attribute__((ext_vector_type(2)));
  bf2_t t = __builtin_amdgcn_cvt_pk_bf16_f32(a, b);
  return __builtin_bit_cast(unsigned int, t);
#else
  return (unsigned int)f2bf(a) | ((unsigned int)f2bf(b) << 16);
#endif
}

__device__ __forceinline__ float fexp2(float x) {
#ifdef HAVE_RAW_EXP2
  return __builtin_amdgcn_exp2f(x);
#else
  return exp2f(x);
#endif
}

// async global->LDS, 16 B/lane; HW writes lds_base + lane*16 (wave-uniform base)
__device__ __forceinline__ void async16(const unsigned short* g, unsigned short* l) {
  __builtin_amdgcn_global_load_lds(
      (const __attribute__((address_space(1))) unsigned int*)g,
      (__attribute__((address_space(3))) unsigned int*)l, 16, 0, 0);
}

// fp32 -> bf16. z=0..3: quarters of x; z=4..7: wq,wk,wv,wo (z==4 scaled by QK_SCALE).
__global__ __launch_bounds__(256) void cvt_kernel(
    const float* __restrict__ x,  unsigned short* __restrict__ xb,
    const float* __restrict__ wq, unsigned short* __restrict__ wqb,
    const float* __restrict__ wk, unsigned short* __restrict__ wkb,
    const float* __restrict__ wv, unsigned short* __restrict__ wvb,
    const float* __restrict__ wo, unsigned short* __restrict__ wob,
    const float* __restrict__ bq, float* __restrict__ bqs)
{
  const int z = blockIdx.y;
  const float* s; unsigned short* d;
  float scale = 1.f;
  if (z < 4)       { s = x + (size_t)z * 1048576; d = xb + (size_t)z * 1048576; }
  else if (z == 4) { s = wq; d = wqb; scale = QK_SCALE; }
  else if (z == 5) { s = wk; d = wkb; }
  else if (z == 6) { s = wv; d = wvb; }
  else             { s = wo; d = wob; }
  const size_t i = ((size_t)blockIdx.x * 256 + threadIdx.x) * 4;
  float4 v = *reinterpret_cast<const float4*>(s + i);
  uint2 o;
  o.x = pkbf(v.x * scale, v.y * scale);
  o.y = pkbf(v.z * scale, v.w * scale);
  *reinterpret_cast<uint2*>(d + i) = o;
  if (z == 4 && blockIdx.x == 0) {
    const int t = threadIdx.x;
    #pragma unroll
    for (int j = 0; j < 4; ++j) bqs[t * 4 + j] = bq[t * 4 + j] * QK_SCALE;
  }
}

// C[m,n] = sum_k A[m,k]*W[n,k] + bias[n]  (NT). bf16 in, fp32 accum.
// BK=32 double-buffered, ONE barrier per K-step, K-loop unrolled x2 (all LDS
// staging destinations compile-time static — r8/r9 lesson). Verified schedule
// (r11 243.97 / r13 244.46 / r17 243.60 / r18 243.01).
// BM template: 128 for QKV (3 blocks/CU; owns the z==2 Vt epilogue);
// 64 for the O-gemm (grid 8x64=512 blocks -> 2 blocks/CU, r18 best-measured).
template <int BM>
__global__ __launch_bounds__(256) void gemm_bt(
    const unsigned short* __restrict__ X,
    const unsigned short* __restrict__ W0, const float* __restrict__ B0, unsigned short* __restrict__ C0,
    const unsigned short* __restrict__ W1, const float* __restrict__ B1, unsigned short* __restrict__ C1,
    const unsigned short* __restrict__ W2, const float* __restrict__ B2, unsigned short* __restrict__ C2,
    float* __restrict__ Cf, unsigned short* __restrict__ VtOut)
{
  const unsigned short* W; const float* Bb; unsigned short* C;
  const int z = blockIdx.z;
  if (z == 0)      { W = W0; Bb = B0; C = C0; }
  else if (z == 1) { W = W1; Bb = B1; C = C1; }
  else             { W = W2; Bb = B2; C = C2; }

  const int bm = blockIdx.y, bn = blockIdx.x;
  const int tid  = threadIdx.x;
  const int lane = tid & 63, wave = tid >> 6;
  const int quad = lane >> 4, n16 = lane & 15;
  constexpr int TM = BM / 32;                 // 16-row frags per wave (4 or 2)
  const int wm = (wave >> 1) * (BM / 2), wn = (wave & 1) * 64;

  __shared__ union {
    struct { unsigned short A[2][BM * 32]; unsigned short B[2][128 * 32]; } s;
    unsigned short T[64 * 136];   // V-transpose staging (z==2, BM==128 only)
  } sm;

  floatx4 zero = {0.f, 0.f, 0.f, 0.f};
  floatx4 acc[TM][4];
  #pragma unroll
  for (int i = 0; i < TM; ++i)
    #pragma unroll
    for (int j = 0; j < 4; ++j) acc[i][j] = zero;

  // staging: wave w stages rows 16w..16w+15 (BM==128: half h adds +64);
  // lane i -> row 16w + i/4, col (i&3)*8
  const int srow = 16 * wave + (lane >> 2);
  const int scol = (lane & 3) * 8;
  const unsigned short* XaL = X + (size_t)(bm * BM + srow) * D + scol;
  const unsigned short* WaL = W + (size_t)(bn * 128 + srow) * D + scol;

  // static per-buffer LDS staging destinations (wave-uniform bases)
  unsigned short* const a0h0 = &sm.s.A[0][(16 * wave) * 32];
  unsigned short* const a1h0 = &sm.s.A[1][(16 * wave) * 32];
  unsigned short* const b0h0 = &sm.s.B[0][(16 * wave) * 32];
  unsigned short* const b0h1 = &sm.s.B[0][(64 + 16 * wave) * 32];
  unsigned short* const b1h0 = &sm.s.B[1][(16 * wave) * 32];
  unsigned short* const b1h1 = &sm.s.B[1][(64 + 16 * wave) * 32];
  unsigned short* const a0h1 = (BM == 128) ? &sm.s.A[0][(64 + 16 * wave) * 32] : a0h0;
  unsigned short* const a1h1 = (BM == 128) ? &sm.s.A[1][(64 + 16 * wave) * 32] : a1h0;

  auto stageA = [&](int k0, unsigned short* h0, unsigned short* h1) {
    async16(XaL + k0, h0);
    if (BM == 128) async16(XaL + (size_t)64 * D + k0, h1);
  };
  auto stageB = [&](int k0, unsigned short* h0, unsigned short* h1) {
    async16(WaL + k0, h0);
    async16(WaL + (size_t)64 * D + k0, h1);
  };

  auto compute32 = [&](const unsigned short* As, const unsigned short* Bs) {
    short8 af[TM], bfr[4];
    #pragma unroll
    for (int t = 0; t < TM; ++t)
      af[t]  = *reinterpret_cast<const short8*>(&As[(wm + t * 16 + n16) * 32 + quad * 8]);
    #pragma unroll
    for (int t = 0; t < 4; ++t)
      bfr[t] = *reinterpret_cast<const short8*>(&Bs[(wn + t * 16 + n16) * 32 + quad * 8]);
    #pragma unroll
    for (int tm = 0; tm < TM; ++tm)
      #pragma unroll
      for (int tn = 0; tn < 4; ++tn)
        acc[tm][tn] = __builtin_amdgcn_mfma_f32_16x16x32_bf16(af[tm], bfr[tn], acc[tm][tn], 0, 0, 0);
  };

  const int NK = D / 32;  // 32 K-steps (even), unrolled 2 -> 16 iterations
  // prologue: stage step 0 into buf0
  stageA(0, a0h0, a0h1);
  stageB(0, b0h0, b0h1);

  for (int kt = 0; kt < NK; kt += 2) {
    // even step: compute buf0 (step kt), stage step kt+1 -> buf1
    __syncthreads();   // drains buf0's loads (issued one compute-phase ago)
    {
      const int k0 = (kt + 1) * 32;   // kt+1 <= 31 < NK always (NK even)
      stageA(k0, a1h0, a1h1);
      stageB(k0, b1h0, b1h1);
    }
    compute32(sm.s.A[0], sm.s.B[0]);

    // odd step: compute buf1 (step kt+1), stage step kt+2 -> buf0
    __syncthreads();   // drains buf1's loads
    if (kt + 2 < NK) {
      const int k0 = (kt + 2) * 32;
      stageA(k0, a0h0, a0h1);
      stageB(k0, b0h0, b0h1);
    }
    compute32(sm.s.A[1], sm.s.B[1]);
  }

  if (BM == 128 && z == 2 && VtOut) {
    // transposed epilogue with sigma key-permutation folded into the global layout:
    // within each 16-key group, 4-key chunks written in order (0,2,1,3).
    #pragma unroll
    for (int p = 0; p < 2; ++p) {
      __syncthreads();
      if ((wn >> 6) == p) {
        #pragma unroll
        for (int tn = 0; tn < 4; ++tn) {
          const int col = bn * 128 + p * 64 + tn * 16 + n16;
          const float bias = Bb[col];
          #pragma unroll
          for (int tm = 0; tm < TM; ++tm) {
            uint2 w;
            w.x = pkbf(acc[tm][tn][0] + bias, acc[tm][tn][1] + bias);
            w.y = pkbf(acc[tm][tn][2] + bias, acc[tm][tn][3] + bias);
            *reinterpret_cast<uint2*>(&sm.T[(tn * 16 + n16) * 136 + wm + tm * 16 + quad * 4]) = w;
          }
        }
      }
      __syncthreads();
      {
        const int rl = tid >> 2, cc = (tid & 3) * 32;
        uint4 t0 = *reinterpret_cast<const uint4*>(&sm.T[rl * 136 + cc]);
        uint4 t1 = *reinterpret_cast<const uint4*>(&sm.T[rl * 136 + cc + 8]);
        uint4 t2 = *reinterpret_cast<const uint4*>(&sm.T[rl * 136 + cc + 16]);
        uint4 t3 = *reinterpret_cast<const uint4*>(&sm.T[rl * 136 + cc + 24]);
        uint4 n0, n1, n2, n3;
        n0.x = t0.x; n0.y = t0.y; n0.z = t1.x; n0.w = t1.y;   // chunks 0,2
        n1.x = t0.z; n1.y = t0.w; n1.z = t1.z; n1.w = t1.w;   // chunks 1,3
        n2.x = t2.x; n2.y = t2.y; n2.z = t3.x; n2.w = t3.y;
        n3.x = t2.z; n3.y = t2.w; n3.z = t3.z; n3.w = t3.w;
        const size_t go = (size_t)(bn * 128 + p * 64 + rl) * S + bm * 128 + cc;
        *reinterpret_cast<uint4*>(&VtOut[go])      = n0;
        *reinterpret_cast<uint4*>(&VtOut[go + 8])  = n1;
        *reinterpret_cast<uint4*>(&VtOut[go + 16]) = n2;
        *reinterpret_cast<uint4*>(&VtOut[go + 24]) = n3;
      }
    }
    return;
  }

  #pragma unroll
  for (int tn = 0; tn < 4; ++tn) {
    const int col = bn * 128 + wn + tn * 16 + n16;
    const float bias = Bb[col];
    #pragma unroll
    for (int tm = 0; tm < TM; ++tm) {
      const int rowb = bm * BM + wm + tm * 16 + quad * 4;
      #pragma unroll
      for (int r = 0; r < 4; ++r) {
        const float v = acc[tm][tn][r] + bias;
        if (Cf) Cf[(size_t)(rowb + r) * D + col] = v;
        else    C[(size_t)(rowb + r) * D + col]  = f2bf(v);
      }
    }
  }
}

// Flash attention (structure verified at 92.4-93.4us): 512 threads, 8 waves
// x one 32-row q-subtile, single-buffer LDS, split-K=NSPLIT, fixed-max exp2
// softmax, VALU row-sums + shfl_xor(32) denominator. ~60 arch VGPR ->
// 4 waves/SIMD, 2 blocks/CU.
// THIS ROUND: s_setprio removed (T5 A/B). Guide evidence: setprio is
// structure-conditional — +4-7% on independent 1-wave blocks (m191) but
// slightly HARMFUL on barrier-lockstep multi-wave structures (m190); ours is
// 8-wave lockstep, closer to m190's regime. Never isolated in-session.
__global__ __launch_bounds__(512, 4) void attn(
    const unsigned short* __restrict__ Q,
    const unsigned short* __restrict__ K,
    const unsigned short* __restrict__ Vt,   // [D][S], sigma-permuted keys
    unsigned short* __restrict__ Op,         // [NSPLIT][S][D] bf16 partial
    float* __restrict__ Ls)                  // [NSPLIT][S][H]
{
  const int h    = blockIdx.y;
  const int z    = blockIdx.z;
  const int q0   = blockIdx.x * 256;
  const int key0 = z * (S / NSPLIT);
  const int tid  = threadIdx.x;
  const int lane = tid & 63, wave = tid >> 6;
  const int l31 = lane & 31, h8 = lane >> 5;

  __shared__ unsigned short Ks[64 * 72];     // [key][d]
  __shared__ unsigned short Vs[64 * 72];     // [d][sigma(key)]

  const int qA = q0 + wave * 32 + l31;
  short8 qfA[4];
  #pragma unroll
  for (int ks = 0; ks < 4; ++ks)
    qfA[ks] = *reinterpret_cast<const short8*>(Q + (size_t)qA * D + h * HD + ks * 16 + h8 * 8);

  floatx16 oA0 = {}, oA1 = {};
  float lsumA = 0.f;

  // staging: 512 threads, 1 uint4 each for K and V (64 rows x 128 B)
  const int r1 = tid >> 3, c8 = (tid & 7) * 8;
  const unsigned short* Kbase = K  + (size_t)(key0 + r1) * D + h * HD + c8;
  const unsigned short* Vbase = Vt + (size_t)(h * HD + r1) * S + key0 + c8;

  uint4 ka, va;
  ka = *reinterpret_cast<const uint4*>(Kbase);
  va = *reinterpret_cast<const uint4*>(Vbase);

  const int NIT = (S / NSPLIT) / 64;  // 32
  for (int kt = 0; kt < NIT; ++kt) {
    __syncthreads();
    *reinterpret_cast<uint4*>(&Ks[r1 * 72 + c8]) = ka;
    *reinterpret_cast<uint4*>(&Vs[r1 * 72 + c8]) = va;
    __syncthreads();

    const int kn = (kt < NIT - 1) ? kt + 1 : kt;
    ka = *reinterpret_cast<const uint4*>(Kbase + (size_t)kn * 64 * D);
    va = *reinterpret_cast<const uint4*>(Vbase + kn * 64);

    // S^T = K . Q^T
    floatx16 sA0 = {}, sA1 = {};
    #pragma unroll
    for (int ks = 0; ks < 4; ++ks) {
      short8 a0 = *reinterpret_cast<const short8*>(&Ks[l31 * 72 + ks * 16 + h8 * 8]);
      short8 a1 = *reinterpret_cast<const short8*>(&Ks[(32 + l31) * 72 + ks * 16 + h8 * 8]);
      sA0 = __builtin_amdgcn_mfma_f32_32x32x16_bf16(a0, qfA[ks], sA0, 0, 0, 0);
      sA1 = __builtin_amdgcn_mfma_f32_32x32x16_bf16(a1, qfA[ks], sA1, 0, 0, 0);
    }

    // fixed-max softmax (exp2 domain) + VALU row-sum accumulation
    #pragma unroll
    for (int r = 0; r < 16; ++r) {
      sA0[r] = fexp2(sA0[r]);
      sA1[r] = fexp2(sA1[r]);
    }
    #pragma unroll
    for (int r = 0; r < 16; ++r) lsumA += sA0[r] + sA1[r];

    // P -> B-frags directly in registers (layout matches sigma-permuted Vs)
    short8 pbA[4];
    {
      unsigned int* ua = reinterpret_cast<unsigned int*>(pbA);
      #pragma unroll
      for (int i = 0; i < 8; ++i) {
        ua[i]     = pkbf(sA0[2 * i], sA0[2 * i + 1]);
        ua[8 + i] = pkbf(sA1[2 * i], sA1[2 * i + 1]);
      }
    }

    // O^T += V~ . P
    #pragma unroll
    for (int ks = 0; ks < 4; ++ks) {
      short8 va0 = *reinterpret_cast<const short8*>(&Vs[l31 * 72 + ks * 16 + h8 * 8]);
      short8 va1 = *reinterpret_cast<const short8*>(&Vs[(32 + l31) * 72 + ks * 16 + h8 * 8]);
      oA0 = __builtin_amdgcn_mfma_f32_32x32x16_bf16(va0, pbA[ks], oA0, 0, 0, 0);
      oA1 = __builtin_amdgcn_mfma_f32_32x32x16_bf16(va1, pbA[ks], oA1, 0, 0, 0);
    }
  }

  // full denominator: this half's 32 key-rows + the other half's 32
  lsumA += __shfl_xor(lsumA, 32, 64);
  if (h8 == 0) Ls[(size_t)z * S * H + qA * H + h] = lsumA;

  unsigned short* obA = Op + (size_t)z * S * D + (size_t)qA * D + h * HD;
  #pragma unroll
  for (int rg = 0; rg < 4; ++rg) {
    uint2 w0, w1;
    w0.x = pkbf(oA0[rg * 4 + 0], oA0[rg * 4 + 1]);
    w0.y = pkbf(oA0[rg * 4 + 2], oA0[rg * 4 + 3]);
    w1.x = pkbf(oA1[rg * 4 + 0], oA1[rg * 4 + 1]);
    w1.y = pkbf(oA1[rg * 4 + 2], oA1[rg * 4 + 3]);
    *reinterpret_cast<uint2*>(&obA[rg * 8 + h8 * 4])      = w0;
    *reinterpret_cast<uint2*>(&obA[32 + rg * 8 + h8 * 4]) = w1;
  }
}

// AO = (sum_z Op[z]) / (sum_z Ls[z]), in-place into Op[0] (bf16). 8 elems/thread.
// Standalone (HBM-BW bound, ~6us); fusing into O-gemm measured +15us (r12).
__global__ __launch_bounds__(256) void combine(
    unsigned short* __restrict__ Op,   // [NSPLIT][S][D], result into split 0
    const float* __restrict__ Ls)      // [NSPLIT][S][H]
{
  const size_t e8 = ((size_t)blockIdx.x * 256 + threadIdx.x) * 8;
  const int q = (int)(e8 >> 10);
  const int col = (int)(e8 & 1023);
  const int hh = col >> 6;
  float l = 0.f;
  #pragma unroll
  for (int z = 0; z < NSPLIT; ++z) l += Ls[(size_t)z * S * H + q * H + hh];
  const float inv = 1.f / l;
  uint4 a[NSPLIT];
  #pragma unroll
  for (int z = 0; z < NSPLIT; ++z)
    a[z] = *reinterpret_cast<const uint4*>(Op + (size_t)z * S * D + e8);
  uint4 r;
  unsigned int* ru = &r.x;
  #pragma unroll
  for (int w = 0; w < 4; ++w) {
    float lo = 0.f, hi = 0.f;
    #pragma unroll
    for (int z = 0; z < NSPLIT; ++z) {
      const unsigned int uw = (&a[z].x)[w];
      union { unsigned int i; float f; } plo, phi;
      plo.i = uw << 16;
      phi.i = uw & 0xFFFF0000u;
      lo += plo.f;
      hi += phi.f;
    }
    ru[w] = pkbf(lo * inv, hi * inv);
  }
  *reinterpret_cast<uint4*>(Op + e8) = r;
}

extern "C" void kernel_launch(void* const* d_in, const int* in_sizes, int n_in,
                              void* d_out, int out_size, void* d_ws, size_t ws_size,
                              hipStream_t stream) {
  const float* x  = (const float*)d_in[0];
  const float* wq = (const float*)d_in[1];
  const float* bq = (const float*)d_in[2];
  const float* wk = (const float*)d_in[3];
  const float* bk = (const float*)d_in[4];
  const float* wv = (const float*)d_in[5];
  const float* bv = (const float*)d_in[6];
  const float* wo = (const float*)d_in[7];
  const float* bo = (const float*)d_in[8];
  float* out = (float*)d_out;

  unsigned short* ws = (unsigned short*)d_ws;
  const size_t SD = (size_t)S * D;
  const size_t DD = (size_t)D * D;
  unsigned short* xb  = ws;
  unsigned short* wqb = xb + SD;
  unsigned short* wkb = wqb + DD;
  unsigned short* wvb = wkb + DD;
  unsigned short* wob = wvb + DD;
  unsigned short* Qw  = wob + DD;
  unsigned short* Kw  = Qw + SD;
  unsigned short* Vtw = Kw + SD;     // [D][S], sigma-permuted keys
  unsigned short* Op  = Vtw + SD;    // [NSPLIT][S][D] bf16 partials, combined in-place
  float* Ls  = (float*)(Op + NSPLIT * SD);  // [NSPLIT][S][H]
  float* bqs = Ls + NSPLIT * (size_t)S * H;

  dim3 blk(256);
  cvt_kernel<<<dim3(1024, 8), blk, 0, stream>>>(x, xb, wq, wqb, wk, wkb, wv, wvb, wo, wob, bq, bqs);
  // Q (pre-scaled to log2 domain), K, V^T(sigma) projections — BM=128 (3 blocks/CU)
  gemm_bt<128><<<dim3(D / 128, S / 128, 3), blk, 0, stream>>>(
      xb, wqb, bqs, Qw, wkb, bk, Kw, wvb, bv, nullptr, nullptr, Vtw);
  // attention: 16 q-tiles x 16 heads x NSPLIT key-splits (512 threads: 8 waves x 32 q)
  attn<<<dim3(S / 256, H, NSPLIT), dim3(512), 0, stream>>>(Qw, Kw, Vtw, Op, Ls);
  // merge splits (in-place into Op[0])
  combine<<<dim3(SD / (256 * 8)), blk, 0, stream>>>(Op, Ls);
  // output projection -> fp32 — BM=64: 512 blocks = 2 blocks/CU
  gemm_bt<64><<<dim3(D / 128, S / 64, 1), blk, 0, stream>>>(
      Op, wob, bo, nullptr, wob, bo, nullptr, wob, bo, nullptr, out, nullptr);
}

// Round 20
// 245.768 us; speedup vs baseline: 1.0001x; 1.0001x over previous
//
#include <hip/hip_runtime.h>
#include <stdint.h>

#define S 4096
#define D 1024
#define H 16
#define HD 64
#define NSPLIT 2

#define QK_SCALE 0.18033688011112042f  // (1/sqrt(64)) * log2(e)

typedef short short8  __attribute__((ext_vector_type(8)));
typedef float floatx4 __attribute__((ext_vector_type(4)));
typedef float floatx16 __attribute__((ext_vector_type(16)));

__device__ __forceinline__ unsigned short f2bf(float f) {
  union { float f; unsigned int i; } x; x.f = f;
  unsigned int r = x.i + 0x7FFFu + ((x.i >> 16) & 1u);
  return (unsigned short)(r >> 16);
}

#if defined(__has_builtin)
#if __has_builtin(__builtin_amdgcn_cvt_pk_bf16_f32)
#define HAVE_PK_BF16 1
#endif
#if __has_builtin(__builtin_amdgcn_exp2f)
#define HAVE_RAW_EXP2 1
#endif
#endif

__device__ __forceinline__ unsigned int pkbf(float a, float b) {
#ifdef HAVE_PK_BF16
  typedef __bf16 bf2_t __attribute__((ext_vector_type(2)));
  bf2_t t = __builtin_amdgcn_cvt_pk_bf16_f32(a, b);
  return __builtin_bit_cast(unsigned int, t);
#else
  return (unsigned int)f2bf(a) | ((unsigned int)f2bf(b) << 16);
#endif
}

__device__ __forceinline__ float fexp2(float x) {
#ifdef HAVE_RAW_EXP2
  return __builtin_amdgcn_exp2f(x);
#else
  return exp2f(x);
#endif
}

// async global->LDS, 16 B/lane; HW writes lds_base + lane*16 (wave-uniform base)
__device__ __forceinline__ void async16(const unsigned short* g, unsigned short* l) {
  __builtin_amdgcn_global_load_lds(
      (const __attribute__((address_space(1))) unsigned int*)g,
      (__attribute__((address_space(3))) unsigned int*)l, 16, 0, 0);
}

// fp32 -> bf16. z=0..3: quarters of x; z=4..7: wq,wk,wv,wo (z==4 scaled by QK_SCALE).
__global__ __launch_bounds__(256) void cvt_kernel(
    const float* __restrict__ x,  unsigned short* __restrict__ xb,
    const float* __restrict__ wq, unsigned short* __restrict__ wqb,
    const float* __restrict__ wk, unsigned short* __restrict__ wkb,
    const float* __restrict__ wv, unsigned short* __restrict__ wvb,
    const float* __restrict__ wo, unsigned short* __restrict__ wob,
    const float* __restrict__ bq, float* __restrict__ bqs)
{
  const int z = blockIdx.y;
  const float* s; unsigned short* d;
  float scale = 1.f;
  if (z < 4)       { s = x + (size_t)z * 1048576; d = xb + (size_t)z * 1048576; }
  else if (z == 4) { s = wq; d = wqb; scale = QK_SCALE; }
  else if (z == 5) { s = wk; d = wkb; }
  else if (z == 6) { s = wv; d = wvb; }
  else             { s = wo; d = wob; }
  const size_t i = ((size_t)blockIdx.x * 256 + threadIdx.x) * 4;
  float4 v = *reinterpret_cast<const float4*>(s + i);
  uint2 o;
  o.x = pkbf(v.x * scale, v.y * scale);
  o.y = pkbf(v.z * scale, v.w * scale);
  *reinterpret_cast<uint2*>(d + i) = o;
  if (z == 4 && blockIdx.x == 0) {
    const int t = threadIdx.x;
    #pragma unroll
    for (int j = 0; j < 4; ++j) bqs[t * 4 + j] = bq[t * 4 + j] * QK_SCALE;
  }
}

// C[m,n] = sum_k A[m,k]*W[n,k] + bias[n]  (NT). bf16 in, fp32 accum.
// BK=32 double-buffered, ONE barrier per K-step, K-loop unrolled x2 (all LDS
// staging destinations compile-time static — r8/r9 lesson). Verified schedule
// (r11 243.97 / r13 244.46 / r17 243.60 / r18 243.01).
// BM template: 128 for QKV (3 blocks/CU; owns the z==2 Vt epilogue);
// 64 for the O-gemm (grid 8x64=512 blocks -> 2 blocks/CU, r18 best-measured).
template <int BM>
__global__ __launch_bounds__(256) void gemm_bt(
    const unsigned short* __restrict__ X,
    const unsigned short* __restrict__ W0, const float* __restrict__ B0, unsigned short* __restrict__ C0,
    const unsigned short* __restrict__ W1, const float* __restrict__ B1, unsigned short* __restrict__ C1,
    const unsigned short* __restrict__ W2, const float* __restrict__ B2, unsigned short* __restrict__ C2,
    float* __restrict__ Cf, unsigned short* __restrict__ VtOut)
{
  const unsigned short* W; const float* Bb; unsigned short* C;
  const int z = blockIdx.z;
  if (z == 0)      { W = W0; Bb = B0; C = C0; }
  else if (z == 1) { W = W1; Bb = B1; C = C1; }
  else             { W = W2; Bb = B2; C = C2; }

  const int bm = blockIdx.y, bn = blockIdx.x;
  const int tid  = threadIdx.x;
  const int lane = tid & 63, wave = tid >> 6;
  const int quad = lane >> 4, n16 = lane & 15;
  constexpr int TM = BM / 32;                 // 16-row frags per wave (4 or 2)
  const int wm = (wave >> 1) * (BM / 2), wn = (wave & 1) * 64;

  __shared__ union {
    struct { unsigned short A[2][BM * 32]; unsigned short B[2][128 * 32]; } s;
    unsigned short T[64 * 136];   // V-transpose staging (z==2, BM==128 only)
  } sm;

  floatx4 zero = {0.f, 0.f, 0.f, 0.f};
  floatx4 acc[TM][4];
  #pragma unroll
  for (int i = 0; i < TM; ++i)
    #pragma unroll
    for (int j = 0; j < 4; ++j) acc[i][j] = zero;

  // staging: wave w stages rows 16w..16w+15 (BM==128: half h adds +64);
  // lane i -> row 16w + i/4, col (i&3)*8
  const int srow = 16 * wave + (lane >> 2);
  const int scol = (lane & 3) * 8;
  const unsigned short* XaL = X + (size_t)(bm * BM + srow) * D + scol;
  const unsigned short* WaL = W + (size_t)(bn * 128 + srow) * D + scol;

  // static per-buffer LDS staging destinations (wave-uniform bases)
  unsigned short* const a0h0 = &sm.s.A[0][(16 * wave) * 32];
  unsigned short* const a1h0 = &sm.s.A[1][(16 * wave) * 32];
  unsigned short* const b0h0 = &sm.s.B[0][(16 * wave) * 32];
  unsigned short* const b0h1 = &sm.s.B[0][(64 + 16 * wave) * 32];
  unsigned short* const b1h0 = &sm.s.B[1][(16 * wave) * 32];
  unsigned short* const b1h1 = &sm.s.B[1][(64 + 16 * wave) * 32];
  unsigned short* const a0h1 = (BM == 128) ? &sm.s.A[0][(64 + 16 * wave) * 32] : a0h0;
  unsigned short* const a1h1 = (BM == 128) ? &sm.s.A[1][(64 + 16 * wave) * 32] : a1h0;

  auto stageA = [&](int k0, unsigned short* h0, unsigned short* h1) {
    async16(XaL + k0, h0);
    if (BM == 128) async16(XaL + (size_t)64 * D + k0, h1);
  };
  auto stageB = [&](int k0, unsigned short* h0, unsigned short* h1) {
    async16(WaL + k0, h0);
    async16(WaL + (size_t)64 * D + k0, h1);
  };

  auto compute32 = [&](const unsigned short* As, const unsigned short* Bs) {
    short8 af[TM], bfr[4];
    #pragma unroll
    for (int t = 0; t < TM; ++t)
      af[t]  = *reinterpret_cast<const short8*>(&As[(wm + t * 16 + n16) * 32 + quad * 8]);
    #pragma unroll
    for (int t = 0; t < 4; ++t)
      bfr[t] = *reinterpret_cast<const short8*>(&Bs[(wn + t * 16 + n16) * 32 + quad * 8]);
    #pragma unroll
    for (int tm = 0; tm < TM; ++tm)
      #pragma unroll
      for (int tn = 0; tn < 4; ++tn)
        acc[tm][tn] = __builtin_amdgcn_mfma_f32_16x16x32_bf16(af[tm], bfr[tn], acc[tm][tn], 0, 0, 0);
  };

  const int NK = D / 32;  // 32 K-steps (even), unrolled 2 -> 16 iterations
  // prologue: stage step 0 into buf0
  stageA(0, a0h0, a0h1);
  stageB(0, b0h0, b0h1);

  for (int kt = 0; kt < NK; kt += 2) {
    // even step: compute buf0 (step kt), stage step kt+1 -> buf1
    __syncthreads();   // drains buf0's loads (issued one compute-phase ago)
    {
      const int k0 = (kt + 1) * 32;   // kt+1 <= 31 < NK always (NK even)
      stageA(k0, a1h0, a1h1);
      stageB(k0, b1h0, b1h1);
    }
    compute32(sm.s.A[0], sm.s.B[0]);

    // odd step: compute buf1 (step kt+1), stage step kt+2 -> buf0
    __syncthreads();   // drains buf1's loads
    if (kt + 2 < NK) {
      const int k0 = (kt + 2) * 32;
      stageA(k0, a0h0, a0h1);
      stageB(k0, b0h0, b0h1);
    }
    compute32(sm.s.A[1], sm.s.B[1]);
  }

  if (BM == 128 && z == 2 && VtOut) {
    // transposed epilogue with sigma key-permutation folded into the global layout:
    // within each 16-key group, 4-key chunks written in order (0,2,1,3).
    #pragma unroll
    for (int p = 0; p < 2; ++p) {
      __syncthreads();
      if ((wn >> 6) == p) {
        #pragma unroll
        for (int tn = 0; tn < 4; ++tn) {
          const int col = bn * 128 + p * 64 + tn * 16 + n16;
          const float bias = Bb[col];
          #pragma unroll
          for (int tm = 0; tm < TM; ++tm) {
            uint2 w;
            w.x = pkbf(acc[tm][tn][0] + bias, acc[tm][tn][1] + bias);
            w.y = pkbf(acc[tm][tn][2] + bias, acc[tm][tn][3] + bias);
            *reinterpret_cast<uint2*>(&sm.T[(tn * 16 + n16) * 136 + wm + tm * 16 + quad * 4]) = w;
          }
        }
      }
      __syncthreads();
      {
        const int rl = tid >> 2, cc = (tid & 3) * 32;
        uint4 t0 = *reinterpret_cast<const uint4*>(&sm.T[rl * 136 + cc]);
        uint4 t1 = *reinterpret_cast<const uint4*>(&sm.T[rl * 136 + cc + 8]);
        uint4 t2 = *reinterpret_cast<const uint4*>(&sm.T[rl * 136 + cc + 16]);
        uint4 t3 = *reinterpret_cast<const uint4*>(&sm.T[rl * 136 + cc + 24]);
        uint4 n0, n1, n2, n3;
        n0.x = t0.x; n0.y = t0.y; n0.z = t1.x; n0.w = t1.y;   // chunks 0,2
        n1.x = t0.z; n1.y = t0.w; n1.z = t1.z; n1.w = t1.w;   // chunks 1,3
        n2.x = t2.x; n2.y = t2.y; n2.z = t3.x; n2.w = t3.y;
        n3.x = t2.z; n3.y = t2.w; n3.z = t3.z; n3.w = t3.w;
        const size_t go = (size_t)(bn * 128 + p * 64 + rl) * S + bm * 128 + cc;
        *reinterpret_cast<uint4*>(&VtOut[go])      = n0;
        *reinterpret_cast<uint4*>(&VtOut[go + 8])  = n1;
        *reinterpret_cast<uint4*>(&VtOut[go + 16]) = n2;
        *reinterpret_cast<uint4*>(&VtOut[go + 24]) = n3;
      }
    }
    return;
  }

  #pragma unroll
  for (int tn = 0; tn < 4; ++tn) {
    const int col = bn * 128 + wn + tn * 16 + n16;
    const float bias = Bb[col];
    #pragma unroll
    for (int tm = 0; tm < TM; ++tm) {
      const int rowb = bm * BM + wm + tm * 16 + quad * 4;
      #pragma unroll
      for (int r = 0; r < 4; ++r) {
        const float v = acc[tm][tn][r] + bias;
        if (Cf) Cf[(size_t)(rowb + r) * D + col] = v;
        else    C[(size_t)(rowb + r) * D + col]  = f2bf(v);
      }
    }
  }
}

// Flash attention (best measured: 90.1us, r19): 512 threads, 8 waves x one
// 32-row q-subtile, single-buffer LDS, split-K=NSPLIT, fixed-max exp2 softmax,
// VALU row-sums + shfl_xor(32) denominator. ~64 VGPR -> 4 waves/SIMD,
// 2 blocks/CU. NO s_setprio: removal measured -3.3% (93.2->90.1, r19 A/B) —
// confirms m190's lockstep-harm for barrier-synced multi-wave structures.
__global__ __launch_bounds__(512, 4) void attn(
    const unsigned short* __restrict__ Q,
    const unsigned short* __restrict__ K,
    const unsigned short* __restrict__ Vt,   // [D][S], sigma-permuted keys
    unsigned short* __restrict__ Op,         // [NSPLIT][S][D] bf16 partial
    float* __restrict__ Ls)                  // [NSPLIT][S][H]
{
  const int h    = blockIdx.y;
  const int z    = blockIdx.z;
  const int q0   = blockIdx.x * 256;
  const int key0 = z * (S / NSPLIT);
  const int tid  = threadIdx.x;
  const int lane = tid & 63, wave = tid >> 6;
  const int l31 = lane & 31, h8 = lane >> 5;

  __shared__ unsigned short Ks[64 * 72];     // [key][d]
  __shared__ unsigned short Vs[64 * 72];     // [d][sigma(key)]

  const int qA = q0 + wave * 32 + l31;
  short8 qfA[4];
  #pragma unroll
  for (int ks = 0; ks < 4; ++ks)
    qfA[ks] = *reinterpret_cast<const short8*>(Q + (size_t)qA * D + h * HD + ks * 16 + h8 * 8);

  floatx16 oA0 = {}, oA1 = {};
  float lsumA = 0.f;

  // staging: 512 threads, 1 uint4 each for K and V (64 rows x 128 B)
  const int r1 = tid >> 3, c8 = (tid & 7) * 8;
  const unsigned short* Kbase = K  + (size_t)(key0 + r1) * D + h * HD + c8;
  const unsigned short* Vbase = Vt + (size_t)(h * HD + r1) * S + key0 + c8;

  uint4 ka, va;
  ka = *reinterpret_cast<const uint4*>(Kbase);
  va = *reinterpret_cast<const uint4*>(Vbase);

  const int NIT = (S / NSPLIT) / 64;  // 32
  for (int kt = 0; kt < NIT; ++kt) {
    __syncthreads();
    *reinterpret_cast<uint4*>(&Ks[r1 * 72 + c8]) = ka;
    *reinterpret_cast<uint4*>(&Vs[r1 * 72 + c8]) = va;
    __syncthreads();

    const int kn = (kt < NIT - 1) ? kt + 1 : kt;
    ka = *reinterpret_cast<const uint4*>(Kbase + (size_t)kn * 64 * D);
    va = *reinterpret_cast<const uint4*>(Vbase + kn * 64);

    // S^T = K . Q^T
    floatx16 sA0 = {}, sA1 = {};
    #pragma unroll
    for (int ks = 0; ks < 4; ++ks) {
      short8 a0 = *reinterpret_cast<const short8*>(&Ks[l31 * 72 + ks * 16 + h8 * 8]);
      short8 a1 = *reinterpret_cast<const short8*>(&Ks[(32 + l31) * 72 + ks * 16 + h8 * 8]);
      sA0 = __builtin_amdgcn_mfma_f32_32x32x16_bf16(a0, qfA[ks], sA0, 0, 0, 0);
      sA1 = __builtin_amdgcn_mfma_f32_32x32x16_bf16(a1, qfA[ks], sA1, 0, 0, 0);
    }

    // fixed-max softmax (exp2 domain) + VALU row-sum accumulation
    #pragma unroll
    for (int r = 0; r < 16; ++r) {
      sA0[r] = fexp2(sA0[r]);
      sA1[r] = fexp2(sA1[r]);
    }
    #pragma unroll
    for (int r = 0; r < 16; ++r) lsumA += sA0[r] + sA1[r];

    // P -> B-frags directly in registers (layout matches sigma-permuted Vs)
    short8 pbA[4];
    {
      unsigned int* ua = reinterpret_cast<unsigned int*>(pbA);
      #pragma unroll
      for (int i = 0; i < 8; ++i) {
        ua[i]     = pkbf(sA0[2 * i], sA0[2 * i + 1]);
        ua[8 + i] = pkbf(sA1[2 * i], sA1[2 * i + 1]);
      }
    }

    // O^T += V~ . P
    #pragma unroll
    for (int ks = 0; ks < 4; ++ks) {
      short8 va0 = *reinterpret_cast<const short8*>(&Vs[l31 * 72 + ks * 16 + h8 * 8]);
      short8 va1 = *reinterpret_cast<const short8*>(&Vs[(32 + l31) * 72 + ks * 16 + h8 * 8]);
      oA0 = __builtin_amdgcn_mfma_f32_32x32x16_bf16(va0, pbA[ks], oA0, 0, 0, 0);
      oA1 = __builtin_amdgcn_mfma_f32_32x32x16_bf16(va1, pbA[ks], oA1, 0, 0, 0);
    }
  }

  // full denominator: this half's 32 key-rows + the other half's 32
  lsumA += __shfl_xor(lsumA, 32, 64);
  if (h8 == 0) Ls[(size_t)z * S * H + qA * H + h] = lsumA;

  unsigned short* obA = Op + (size_t)z * S * D + (size_t)qA * D + h * HD;
  #pragma unroll
  for (int rg = 0; rg < 4; ++rg) {
    uint2 w0, w1;
    w0.x = pkbf(oA0[rg * 4 + 0], oA0[rg * 4 + 1]);
    w0.y = pkbf(oA0[rg * 4 + 2], oA0[rg * 4 + 3]);
    w1.x = pkbf(oA1[rg * 4 + 0], oA1[rg * 4 + 1]);
    w1.y = pkbf(oA1[rg * 4 + 2], oA1[rg * 4 + 3]);
    *reinterpret_cast<uint2*>(&obA[rg * 8 + h8 * 4])      = w0;
    *reinterpret_cast<uint2*>(&obA[32 + rg * 8 + h8 * 4]) = w1;
  }
}

// AO = (sum_z Op[z]) / (sum_z Ls[z]), in-place into Op[0] (bf16). 8 elems/thread.
// Standalone (HBM-BW bound, ~6us); fusing into O-gemm measured +15us (r12).
__global__ __launch_bounds__(256) void combine(
    unsigned short* __restrict__ Op,   // [NSPLIT][S][D], result into split 0
    const float* __restrict__ Ls)      // [NSPLIT][S][H]
{
  const size_t e8 = ((size_t)blockIdx.x * 256 + threadIdx.x) * 8;
  const int q = (int)(e8 >> 10);
  const int col = (int)(e8 & 1023);
  const int hh = col >> 6;
  float l = 0.f;
  #pragma unroll
  for (int z = 0; z < NSPLIT; ++z) l += Ls[(size_t)z * S * H + q * H + hh];
  const float inv = 1.f / l;
  uint4 a[NSPLIT];
  #pragma unroll
  for (int z = 0; z < NSPLIT; ++z)
    a[z] = *reinterpret_cast<const uint4*>(Op + (size_t)z * S * D + e8);
  uint4 r;
  unsigned int* ru = &r.x;
  #pragma unroll
  for (int w = 0; w < 4; ++w) {
    float lo = 0.f, hi = 0.f;
    #pragma unroll
    for (int z = 0; z < NSPLIT; ++z) {
      const unsigned int uw = (&a[z].x)[w];
      union { unsigned int i; float f; } plo, phi;
      plo.i = uw << 16;
      phi.i = uw & 0xFFFF0000u;
      lo += plo.f;
      hi += phi.f;
    }
    ru[w] = pkbf(lo * inv, hi * inv);
  }
  *reinterpret_cast<uint4*>(Op + e8) = r;
}

extern "C" void kernel_launch(void* const* d_in, const int* in_sizes, int n_in,
                              void* d_out, int out_size, void* d_ws, size_t ws_size,
                              hipStream_t stream) {
  const float* x  = (const float*)d_in[0];
  const float* wq = (const float*)d_in[1];
  const float* bq = (const float*)d_in[2];
  const float* wk = (const float*)d_in[3];
  const float* bk = (const float*)d_in[4];
  const float* wv = (const float*)d_in[5];
  const float* bv = (const float*)d_in[6];
  const float* wo = (const float*)d_in[7];
  const float* bo = (const float*)d_in[8];
  float* out = (float*)d_out;

  unsigned short* ws = (unsigned short*)d_ws;
  const size_t SD = (size_t)S * D;
  const size_t DD = (size_t)D * D;
  unsigned short* xb  = ws;
  unsigned short* wqb = xb + SD;
  unsigned short* wkb = wqb + DD;
  unsigned short* wvb = wkb + DD;
  unsigned short* wob = wvb + DD;
  unsigned short* Qw  = wob + DD;
  unsigned short* Kw  = Qw + SD;
  unsigned short* Vtw = Kw + SD;     // [D][S], sigma-permuted keys
  unsigned short* Op  = Vtw + SD;    // [NSPLIT][S][D] bf16 partials, combined in-place
  float* Ls  = (float*)(Op + NSPLIT * SD);  // [NSPLIT][S][H]
  float* bqs = Ls + NSPLIT * (size_t)S * H;

  dim3 blk(256);
  cvt_kernel<<<dim3(1024, 8), blk, 0, stream>>>(x, xb, wq, wqb, wk, wkb, wv, wvb, wo, wob, bq, bqs);
  // Q (pre-scaled to log2 domain), K, V^T(sigma) projections — BM=128 (3 blocks/CU)
  gemm_bt<128><<<dim3(D / 128, S / 128, 3), blk, 0, stream>>>(
      xb, wqb, bqs, Qw, wkb, bk, Kw, wvb, bv, nullptr, nullptr, Vtw);
  // attention: 16 q-tiles x 16 heads x NSPLIT key-splits (512 threads: 8 waves x 32 q)
  attn<<<dim3(S / 256, H, NSPLIT), dim3(512), 0, stream>>>(Qw, Kw, Vtw, Op, Ls);
  // merge splits (in-place into Op[0])
  combine<<<dim3(SD / (256 * 8)), blk, 0, stream>>>(Op, Ls);
  // output projection -> fp32 — BM=64: 512 blocks = 2 blocks/CU
  gemm_bt<64><<<dim3(D / 128, S / 64, 1), blk, 0, stream>>>(
      Op, wob, bo, nullptr, wob, bo, nullptr, wob, bo, nullptr, out, nullptr);
}

// Round 21
// 242.163 us; speedup vs baseline: 1.0150x; 1.0149x over previous
//
#include <hip/hip_runtime.h>
#include <stdint.h>

#define S 4096
#define D 1024
#define H 16
#define HD 64
#define NSPLIT 2

#define QK_SCALE 0.18033688011112042f  // (1/sqrt(64)) * log2(e)

typedef short short8  __attribute__((ext_vector_type(8)));
typedef float floatx4 __attribute__((ext_vector_type(4)));
typedef float floatx16 __attribute__((ext_vector_type(16)));

__device__ __forceinline__ unsigned short f2bf(float f) {
  union { float f; unsigned int i; } x; x.f = f;
  unsigned int r = x.i + 0x7FFFu + ((x.i >> 16) & 1u);
  return (unsigned short)(r >> 16);
}

#if defined(__has_builtin)
#if __has_builtin(__builtin_amdgcn_cvt_pk_bf16_f32)
#define HAVE_PK_BF16 1
#endif
#if __has_builtin(__builtin_amdgcn_exp2f)
#define HAVE_RAW_EXP2 1
#endif
#endif

__device__ __forceinline__ unsigned int pkbf(float a, float b) {
#ifdef HAVE_PK_BF16
  typedef __bf16 bf2_t __attribute__((ext_vector_type(2)));
  bf2_t t = __builtin_amdgcn_cvt_pk_bf16_f32(a, b);
  return __builtin_bit_cast(unsigned int, t);
#else
  return (unsigned int)f2bf(a) | ((unsigned int)f2bf(b) << 16);
#endif
}

__device__ __forceinline__ float fexp2(float x) {
#ifdef HAVE_RAW_EXP2
  return __builtin_amdgcn_exp2f(x);
#else
  return exp2f(x);
#endif
}

// async global->LDS, 16 B/lane; HW writes lds_base + lane*16 (wave-uniform base)
__device__ __forceinline__ void async16(const unsigned short* g, unsigned short* l) {
  __builtin_amdgcn_global_load_lds(
      (const __attribute__((address_space(1))) unsigned int*)g,
      (__attribute__((address_space(3))) unsigned int*)l, 16, 0, 0);
}

// fp32 -> bf16. z=0..3: quarters of x; z=4..7: wq,wk,wv,wo (z==4 scaled by QK_SCALE).
__global__ __launch_bounds__(256) void cvt_kernel(
    const float* __restrict__ x,  unsigned short* __restrict__ xb,
    const float* __restrict__ wq, unsigned short* __restrict__ wqb,
    const float* __restrict__ wk, unsigned short* __restrict__ wkb,
    const float* __restrict__ wv, unsigned short* __restrict__ wvb,
    const float* __restrict__ wo, unsigned short* __restrict__ wob,
    const float* __restrict__ bq, float* __restrict__ bqs)
{
  const int z = blockIdx.y;
  const float* s; unsigned short* d;
  float scale = 1.f;
  if (z < 4)       { s = x + (size_t)z * 1048576; d = xb + (size_t)z * 1048576; }
  else if (z == 4) { s = wq; d = wqb; scale = QK_SCALE; }
  else if (z == 5) { s = wk; d = wkb; }
  else if (z == 6) { s = wv; d = wvb; }
  else             { s = wo; d = wob; }
  const size_t i = ((size_t)blockIdx.x * 256 + threadIdx.x) * 4;
  float4 v = *reinterpret_cast<const float4*>(s + i);
  uint2 o;
  o.x = pkbf(v.x * scale, v.y * scale);
  o.y = pkbf(v.z * scale, v.w * scale);
  *reinterpret_cast<uint2*>(d + i) = o;
  if (z == 4 && blockIdx.x == 0) {
    const int t = threadIdx.x;
    #pragma unroll
    for (int j = 0; j < 4; ++j) bqs[t * 4 + j] = bq[t * 4 + j] * QK_SCALE;
  }
}

// C[m,n] = sum_k A[m,k]*W[n,k] + bias[n]  (NT). bf16 in, fp32 accum.
// BK=32 double-buffered, ONE barrier per K-step, K-loop unrolled x2 (all LDS
// staging destinations compile-time static — r8/r9 lesson). Verified schedule
// (r11 243.97 / r13 244.46 / r17 243.60 / r18 243.01 total).
// BM template: 128 for QKV (3 blocks/CU; owns the z==2 Vt epilogue);
// 64 for the O-gemm (grid 8x64=512 blocks -> 2 blocks/CU, r18 best-measured).
template <int BM>
__global__ __launch_bounds__(256) void gemm_bt(
    const unsigned short* __restrict__ X,
    const unsigned short* __restrict__ W0, const float* __restrict__ B0, unsigned short* __restrict__ C0,
    const unsigned short* __restrict__ W1, const float* __restrict__ B1, unsigned short* __restrict__ C1,
    const unsigned short* __restrict__ W2, const float* __restrict__ B2, unsigned short* __restrict__ C2,
    float* __restrict__ Cf, unsigned short* __restrict__ VtOut)
{
  const unsigned short* W; const float* Bb; unsigned short* C;
  const int z = blockIdx.z;
  if (z == 0)      { W = W0; Bb = B0; C = C0; }
  else if (z == 1) { W = W1; Bb = B1; C = C1; }
  else             { W = W2; Bb = B2; C = C2; }

  const int bm = blockIdx.y, bn = blockIdx.x;
  const int tid  = threadIdx.x;
  const int lane = tid & 63, wave = tid >> 6;
  const int quad = lane >> 4, n16 = lane & 15;
  constexpr int TM = BM / 32;                 // 16-row frags per wave (4 or 2)
  const int wm = (wave >> 1) * (BM / 2), wn = (wave & 1) * 64;

  __shared__ union {
    struct { unsigned short A[2][BM * 32]; unsigned short B[2][128 * 32]; } s;
    unsigned short T[64 * 136];   // V-transpose staging (z==2, BM==128 only)
  } sm;

  floatx4 zero = {0.f, 0.f, 0.f, 0.f};
  floatx4 acc[TM][4];
  #pragma unroll
  for (int i = 0; i < TM; ++i)
    #pragma unroll
    for (int j = 0; j < 4; ++j) acc[i][j] = zero;

  // staging: wave w stages rows 16w..16w+15 (BM==128: half h adds +64);
  // lane i -> row 16w + i/4, col (i&3)*8
  const int srow = 16 * wave + (lane >> 2);
  const int scol = (lane & 3) * 8;
  const unsigned short* XaL = X + (size_t)(bm * BM + srow) * D + scol;
  const unsigned short* WaL = W + (size_t)(bn * 128 + srow) * D + scol;

  // static per-buffer LDS staging destinations (wave-uniform bases)
  unsigned short* const a0h0 = &sm.s.A[0][(16 * wave) * 32];
  unsigned short* const a1h0 = &sm.s.A[1][(16 * wave) * 32];
  unsigned short* const b0h0 = &sm.s.B[0][(16 * wave) * 32];
  unsigned short* const b0h1 = &sm.s.B[0][(64 + 16 * wave) * 32];
  unsigned short* const b1h0 = &sm.s.B[1][(16 * wave) * 32];
  unsigned short* const b1h1 = &sm.s.B[1][(64 + 16 * wave) * 32];
  unsigned short* const a0h1 = (BM == 128) ? &sm.s.A[0][(64 + 16 * wave) * 32] : a0h0;
  unsigned short* const a1h1 = (BM == 128) ? &sm.s.A[1][(64 + 16 * wave) * 32] : a1h0;

  auto stageA = [&](int k0, unsigned short* h0, unsigned short* h1) {
    async16(XaL + k0, h0);
    if (BM == 128) async16(XaL + (size_t)64 * D + k0, h1);
  };
  auto stageB = [&](int k0, unsigned short* h0, unsigned short* h1) {
    async16(WaL + k0, h0);
    async16(WaL + (size_t)64 * D + k0, h1);
  };

  auto compute32 = [&](const unsigned short* As, const unsigned short* Bs) {
    short8 af[TM], bfr[4];
    #pragma unroll
    for (int t = 0; t < TM; ++t)
      af[t]  = *reinterpret_cast<const short8*>(&As[(wm + t * 16 + n16) * 32 + quad * 8]);
    #pragma unroll
    for (int t = 0; t < 4; ++t)
      bfr[t] = *reinterpret_cast<const short8*>(&Bs[(wn + t * 16 + n16) * 32 + quad * 8]);
    #pragma unroll
    for (int tm = 0; tm < TM; ++tm)
      #pragma unroll
      for (int tn = 0; tn < 4; ++tn)
        acc[tm][tn] = __builtin_amdgcn_mfma_f32_16x16x32_bf16(af[tm], bfr[tn], acc[tm][tn], 0, 0, 0);
  };

  const int NK = D / 32;  // 32 K-steps (even), unrolled 2 -> 16 iterations
  // prologue: stage step 0 into buf0
  stageA(0, a0h0, a0h1);
  stageB(0, b0h0, b0h1);

  for (int kt = 0; kt < NK; kt += 2) {
    // even step: compute buf0 (step kt), stage step kt+1 -> buf1
    __syncthreads();   // drains buf0's loads (issued one compute-phase ago)
    {
      const int k0 = (kt + 1) * 32;   // kt+1 <= 31 < NK always (NK even)
      stageA(k0, a1h0, a1h1);
      stageB(k0, b1h0, b1h1);
    }
    compute32(sm.s.A[0], sm.s.B[0]);

    // odd step: compute buf1 (step kt+1), stage step kt+2 -> buf0
    __syncthreads();   // drains buf1's loads
    if (kt + 2 < NK) {
      const int k0 = (kt + 2) * 32;
      stageA(k0, a0h0, a0h1);
      stageB(k0, b0h0, b0h1);
    }
    compute32(sm.s.A[1], sm.s.B[1]);
  }

  if (BM == 128 && z == 2 && VtOut) {
    // transposed epilogue with sigma key-permutation folded into the global layout:
    // within each 16-key group, 4-key chunks written in order (0,2,1,3).
    #pragma unroll
    for (int p = 0; p < 2; ++p) {
      __syncthreads();
      if ((wn >> 6) == p) {
        #pragma unroll
        for (int tn = 0; tn < 4; ++tn) {
          const int col = bn * 128 + p * 64 + tn * 16 + n16;
          const float bias = Bb[col];
          #pragma unroll
          for (int tm = 0; tm < TM; ++tm) {
            uint2 w;
            w.x = pkbf(acc[tm][tn][0] + bias, acc[tm][tn][1] + bias);
            w.y = pkbf(acc[tm][tn][2] + bias, acc[tm][tn][3] + bias);
            *reinterpret_cast<uint2*>(&sm.T[(tn * 16 + n16) * 136 + wm + tm * 16 + quad * 4]) = w;
          }
        }
      }
      __syncthreads();
      {
        const int rl = tid >> 2, cc = (tid & 3) * 32;
        uint4 t0 = *reinterpret_cast<const uint4*>(&sm.T[rl * 136 + cc]);
        uint4 t1 = *reinterpret_cast<const uint4*>(&sm.T[rl * 136 + cc + 8]);
        uint4 t2 = *reinterpret_cast<const uint4*>(&sm.T[rl * 136 + cc + 16]);
        uint4 t3 = *reinterpret_cast<const uint4*>(&sm.T[rl * 136 + cc + 24]);
        uint4 n0, n1, n2, n3;
        n0.x = t0.x; n0.y = t0.y; n0.z = t1.x; n0.w = t1.y;   // chunks 0,2
        n1.x = t0.z; n1.y = t0.w; n1.z = t1.z; n1.w = t1.w;   // chunks 1,3
        n2.x = t2.x; n2.y = t2.y; n2.z = t3.x; n2.w = t3.y;
        n3.x = t2.z; n3.y = t2.w; n3.z = t3.z; n3.w = t3.w;
        const size_t go = (size_t)(bn * 128 + p * 64 + rl) * S + bm * 128 + cc;
        *reinterpret_cast<uint4*>(&VtOut[go])      = n0;
        *reinterpret_cast<uint4*>(&VtOut[go + 8])  = n1;
        *reinterpret_cast<uint4*>(&VtOut[go + 16]) = n2;
        *reinterpret_cast<uint4*>(&VtOut[go + 24]) = n3;
      }
    }
    return;
  }

  #pragma unroll
  for (int tn = 0; tn < 4; ++tn) {
    const int col = bn * 128 + wn + tn * 16 + n16;
    const float bias = Bb[col];
    #pragma unroll
    for (int tm = 0; tm < TM; ++tm) {
      const int rowb = bm * BM + wm + tm * 16 + quad * 4;
      #pragma unroll
      for (int r = 0; r < 4; ++r) {
        const float v = acc[tm][tn][r] + bias;
        if (Cf) Cf[(size_t)(rowb + r) * D + col] = v;
        else    C[(size_t)(rowb + r) * D + col]  = f2bf(v);
      }
    }
  }
}

// Flash attention: 512 threads, 8 waves x one 32-row q-subtile, single-buffer
// LDS, split-K=NSPLIT, fixed-max exp2 softmax, VALU row-sums + shfl_xor(32)
// denominator. ~60 VGPR -> 4 waves/SIMD, 2 blocks/CU.
// setprio KEPT: r19/r20 A/B showed removal speeds the isolated dispatch
// (93.2->90-92) but the END-TO-END total regresses +2.5-2.8us reproducibly
// (245.8 x2 vs 243.0); graded metric is total -> keep setprio.
__global__ __launch_bounds__(512, 4) void attn(
    const unsigned short* __restrict__ Q,
    const unsigned short* __restrict__ K,
    const unsigned short* __restrict__ Vt,   // [D][S], sigma-permuted keys
    unsigned short* __restrict__ Op,         // [NSPLIT][S][D] bf16 partial
    float* __restrict__ Ls)                  // [NSPLIT][S][H]
{
  const int h    = blockIdx.y;
  const int z    = blockIdx.z;
  const int q0   = blockIdx.x * 256;
  const int key0 = z * (S / NSPLIT);
  const int tid  = threadIdx.x;
  const int lane = tid & 63, wave = tid >> 6;
  const int l31 = lane & 31, h8 = lane >> 5;

  __shared__ unsigned short Ks[64 * 72];     // [key][d]
  __shared__ unsigned short Vs[64 * 72];     // [d][sigma(key)]

  const int qA = q0 + wave * 32 + l31;
  short8 qfA[4];
  #pragma unroll
  for (int ks = 0; ks < 4; ++ks)
    qfA[ks] = *reinterpret_cast<const short8*>(Q + (size_t)qA * D + h * HD + ks * 16 + h8 * 8);

  floatx16 oA0 = {}, oA1 = {};
  float lsumA = 0.f;

  // staging: 512 threads, 1 uint4 each for K and V (64 rows x 128 B)
  const int r1 = tid >> 3, c8 = (tid & 7) * 8;
  const unsigned short* Kbase = K  + (size_t)(key0 + r1) * D + h * HD + c8;
  const unsigned short* Vbase = Vt + (size_t)(h * HD + r1) * S + key0 + c8;

  uint4 ka, va;
  ka = *reinterpret_cast<const uint4*>(Kbase);
  va = *reinterpret_cast<const uint4*>(Vbase);

  const int NIT = (S / NSPLIT) / 64;  // 32
  for (int kt = 0; kt < NIT; ++kt) {
    __syncthreads();
    *reinterpret_cast<uint4*>(&Ks[r1 * 72 + c8]) = ka;
    *reinterpret_cast<uint4*>(&Vs[r1 * 72 + c8]) = va;
    __syncthreads();

    const int kn = (kt < NIT - 1) ? kt + 1 : kt;
    ka = *reinterpret_cast<const uint4*>(Kbase + (size_t)kn * 64 * D);
    va = *reinterpret_cast<const uint4*>(Vbase + kn * 64);

    // S^T = K . Q^T
    floatx16 sA0 = {}, sA1 = {};
    __builtin_amdgcn_s_setprio(1);
    #pragma unroll
    for (int ks = 0; ks < 4; ++ks) {
      short8 a0 = *reinterpret_cast<const short8*>(&Ks[l31 * 72 + ks * 16 + h8 * 8]);
      short8 a1 = *reinterpret_cast<const short8*>(&Ks[(32 + l31) * 72 + ks * 16 + h8 * 8]);
      sA0 = __builtin_amdgcn_mfma_f32_32x32x16_bf16(a0, qfA[ks], sA0, 0, 0, 0);
      sA1 = __builtin_amdgcn_mfma_f32_32x32x16_bf16(a1, qfA[ks], sA1, 0, 0, 0);
    }
    __builtin_amdgcn_s_setprio(0);

    // fixed-max softmax (exp2 domain) + VALU row-sum accumulation
    #pragma unroll
    for (int r = 0; r < 16; ++r) {
      sA0[r] = fexp2(sA0[r]);
      sA1[r] = fexp2(sA1[r]);
    }
    #pragma unroll
    for (int r = 0; r < 16; ++r) lsumA += sA0[r] + sA1[r];

    // P -> B-frags directly in registers (layout matches sigma-permuted Vs)
    short8 pbA[4];
    {
      unsigned int* ua = reinterpret_cast<unsigned int*>(pbA);
      #pragma unroll
      for (int i = 0; i < 8; ++i) {
        ua[i]     = pkbf(sA0[2 * i], sA0[2 * i + 1]);
        ua[8 + i] = pkbf(sA1[2 * i], sA1[2 * i + 1]);
      }
    }

    // O^T += V~ . P
    __builtin_amdgcn_s_setprio(1);
    #pragma unroll
    for (int ks = 0; ks < 4; ++ks) {
      short8 va0 = *reinterpret_cast<const short8*>(&Vs[l31 * 72 + ks * 16 + h8 * 8]);
      short8 va1 = *reinterpret_cast<const short8*>(&Vs[(32 + l31) * 72 + ks * 16 + h8 * 8]);
      oA0 = __builtin_amdgcn_mfma_f32_32x32x16_bf16(va0, pbA[ks], oA0, 0, 0, 0);
      oA1 = __builtin_amdgcn_mfma_f32_32x32x16_bf16(va1, pbA[ks], oA1, 0, 0, 0);
    }
    __builtin_amdgcn_s_setprio(0);
  }

  // full denominator: this half's 32 key-rows + the other half's 32
  lsumA += __shfl_xor(lsumA, 32, 64);
  if (h8 == 0) Ls[(size_t)z * S * H + qA * H + h] = lsumA;

  unsigned short* obA = Op + (size_t)z * S * D + (size_t)qA * D + h * HD;
  #pragma unroll
  for (int rg = 0; rg < 4; ++rg) {
    uint2 w0, w1;
    w0.x = pkbf(oA0[rg * 4 + 0], oA0[rg * 4 + 1]);
    w0.y = pkbf(oA0[rg * 4 + 2], oA0[rg * 4 + 3]);
    w1.x = pkbf(oA1[rg * 4 + 0], oA1[rg * 4 + 1]);
    w1.y = pkbf(oA1[rg * 4 + 2], oA1[rg * 4 + 3]);
    *reinterpret_cast<uint2*>(&obA[rg * 8 + h8 * 4])      = w0;
    *reinterpret_cast<uint2*>(&obA[32 + rg * 8 + h8 * 4]) = w1;
  }
}

// AO = (sum_z Op[z]) / (sum_z Ls[z]), in-place into Op[0] (bf16). 8 elems/thread.
// Standalone (HBM-BW bound, ~6us); fusing into O-gemm measured +15us (r12).
__global__ __launch_bounds__(256) void combine(
    unsigned short* __restrict__ Op,   // [NSPLIT][S][D], result into split 0
    const float* __restrict__ Ls)      // [NSPLIT][S][H]
{
  const size_t e8 = ((size_t)blockIdx.x * 256 + threadIdx.x) * 8;
  const int q = (int)(e8 >> 10);
  const int col = (int)(e8 & 1023);
  const int hh = col >> 6;
  float l = 0.f;
  #pragma unroll
  for (int z = 0; z < NSPLIT; ++z) l += Ls[(size_t)z * S * H + q * H + hh];
  const float inv = 1.f / l;
  uint4 a[NSPLIT];
  #pragma unroll
  for (int z = 0; z < NSPLIT; ++z)
    a[z] = *reinterpret_cast<const uint4*>(Op + (size_t)z * S * D + e8);
  uint4 r;
  unsigned int* ru = &r.x;
  #pragma unroll
  for (int w = 0; w < 4; ++w) {
    float lo = 0.f, hi = 0.f;
    #pragma unroll
    for (int z = 0; z < NSPLIT; ++z) {
      const unsigned int uw = (&a[z].x)[w];
      union { unsigned int i; float f; } plo, phi;
      plo.i = uw << 16;
      phi.i = uw & 0xFFFF0000u;
      lo += plo.f;
      hi += phi.f;
    }
    ru[w] = pkbf(lo * inv, hi * inv);
  }
  *reinterpret_cast<uint4*>(Op + e8) = r;
}

extern "C" void kernel_launch(void* const* d_in, const int* in_sizes, int n_in,
                              void* d_out, int out_size, void* d_ws, size_t ws_size,
                              hipStream_t stream) {
  const float* x  = (const float*)d_in[0];
  const float* wq = (const float*)d_in[1];
  const float* bq = (const float*)d_in[2];
  const float* wk = (const float*)d_in[3];
  const float* bk = (const float*)d_in[4];
  const float* wv = (const float*)d_in[5];
  const float* bv = (const float*)d_in[6];
  const float* wo = (const float*)d_in[7];
  const float* bo = (const float*)d_in[8];
  float* out = (float*)d_out;

  unsigned short* ws = (unsigned short*)d_ws;
  const size_t SD = (size_t)S * D;
  const size_t DD = (size_t)D * D;
  unsigned short* xb  = ws;
  unsigned short* wqb = xb + SD;
  unsigned short* wkb = wqb + DD;
  unsigned short* wvb = wkb + DD;
  unsigned short* wob = wvb + DD;
  unsigned short* Qw  = wob + DD;
  unsigned short* Kw  = Qw + SD;
  unsigned short* Vtw = Kw + SD;     // [D][S], sigma-permuted keys
  unsigned short* Op  = Vtw + SD;    // [NSPLIT][S][D] bf16 partials, combined in-place
  float* Ls  = (float*)(Op + NSPLIT * SD);  // [NSPLIT][S][H]
  float* bqs = Ls + NSPLIT * (size_t)S * H;

  dim3 blk(256);
  cvt_kernel<<<dim3(1024, 8), blk, 0, stream>>>(x, xb, wq, wqb, wk, wkb, wv, wvb, wo, wob, bq, bqs);
  // Q (pre-scaled to log2 domain), K, V^T(sigma) projections — BM=128 (3 blocks/CU)
  gemm_bt<128><<<dim3(D / 128, S / 128, 3), blk, 0, stream>>>(
      xb, wqb, bqs, Qw, wkb, bk, Kw, wvb, bv, nullptr, nullptr, Vtw);
  // attention: 16 q-tiles x 16 heads x NSPLIT key-splits (512 threads: 8 waves x 32 q)
  attn<<<dim3(S / 256, H, NSPLIT), dim3(512), 0, stream>>>(Qw, Kw, Vtw, Op, Ls);
  // merge splits (in-place into Op[0])
  combine<<<dim3(SD / (256 * 8)), blk, 0, stream>>>(Op, Ls);
  // output projection -> fp32 — BM=64: 512 blocks = 2 blocks/CU
  gemm_bt<64><<<dim3(D / 128, S / 64, 1), blk, 0, stream>>>(
      Op, wob, bo, nullptr, wob, bo, nullptr, wob, bo, nullptr, out, nullptr);
}